// Round 1
// baseline (149.271 us; speedup 1.0000x reference)
//
#include <hip/hip_runtime.h>

// GroundTruthBasedPriorNetwork: mus = W2·tanh(W1·gather(gt,parents)+b1)+b2, logvars = 0
// Shapes: gt[B,64] f32, W1[64,16,8], b1[64,16], W2[64,16], b2[64], parent_idx[64,8] i32
// Output: mus [B*64] then logvars [B*64], both f32.
//
// Design: lane = node (64 lanes = 64 nodes), wave streams batch rows.
//  - weights per node live in VGPRs (loaded once, ~161 floats/lane)
//  - parent gather = 8 ds_bpermute shuffles of the row value (parents are lanes
//    of the same wave; padded parent slots hit zeroed W1 columns -> no mask)
//  - float2 ext-vector math -> v_pk_fma_f32 (2x fp32 rate)
//  - tanh via Pade(5,4) rational + clamp(+-3.5): 1 v_rcp per tanh, max err ~1.1e-3
//    -> mus worst-case err ~4.4e-3 << 2.73e-2 threshold

#define BATCH   131072
#define NODES   64
#define HID     16
#define MAXP    8
#define NBLOCKS 512
#define TPB     256
#define NWAVES  (NBLOCKS * (TPB / 64))   // 2048
#define ROWS    (BATCH / NWAVES)         // 64

typedef float v2 __attribute__((ext_vector_type(2)));

__device__ __forceinline__ v2 tanh2(v2 x) {
    const v2 hi = {  3.5f,  3.5f };
    const v2 lo = { -3.5f, -3.5f };
    x = __builtin_elementwise_min(x, hi);
    x = __builtin_elementwise_max(x, lo);
    v2 x2  = x * x;
    v2 num = x2 * (x2 + 105.f) + 945.f;          // 945 + 105 x^2 + x^4
    v2 den = x2 * (x2 * 15.f + 420.f) + 945.f;   // 945 + 420 x^2 + 15 x^4
    v2 r;
    r.x = __builtin_amdgcn_rcpf(den.x);
    r.y = __builtin_amdgcn_rcpf(den.y);
    return x * num * r;
}

__global__ __launch_bounds__(TPB, 2)
void prior_kernel(const float* __restrict__ gt,
                  const float* __restrict__ W1,
                  const float* __restrict__ b1,
                  const float* __restrict__ W2,
                  const float* __restrict__ b2,
                  const int*   __restrict__ parent_idx,
                  float* __restrict__ out)
{
    const int lane = threadIdx.x & 63;
    const int n    = lane;                                   // node index
    const int wave = blockIdx.x * (TPB / 64) + (threadIdx.x >> 6);

    // ---- one-time: node-n weights into registers ----
    v2 w1r[8][8];   // [h-pair][p] = {W1[n][2h][p], W1[n][2h+1][p]}
    const float* w1p = W1 + n * (HID * MAXP);
    #pragma unroll
    for (int h2 = 0; h2 < 8; ++h2) {
        #pragma unroll
        for (int p = 0; p < 8; ++p) {
            v2 t = { w1p[(2 * h2) * MAXP + p], w1p[(2 * h2 + 1) * MAXP + p] };
            w1r[h2][p] = t;
        }
    }
    v2 b1r[8], w2r[8];
    #pragma unroll
    for (int h2 = 0; h2 < 8; ++h2) {
        v2 tb = { b1[n * HID + 2 * h2], b1[n * HID + 2 * h2 + 1] };
        v2 tw = { W2[n * HID + 2 * h2], W2[n * HID + 2 * h2 + 1] };
        b1r[h2] = tb;
        w2r[h2] = tw;
    }
    const float b2s = b2[n];
    int pidx[8];
    #pragma unroll
    for (int p = 0; p < 8; ++p) pidx[p] = parent_idx[n * MAXP + p];

    // ---- stream batch rows (interleaved: concurrent waves touch contiguous rows) ----
    int   b     = wave;
    float g     = gt[b * NODES + n];
    float gnext = 0.f;
    for (int r = 0; r < ROWS; ++r) {
        const int bn = b + NWAVES;
        if (r + 1 < ROWS) gnext = gt[bn * NODES + n];   // prefetch next row

        // gather the 8 parent values from sibling lanes
        float x[8];
        #pragma unroll
        for (int p = 0; p < 8; ++p) x[p] = __shfl(g, pidx[p], 64);

        v2 mu2 = { 0.f, 0.f };
        #pragma unroll
        for (int h2 = 0; h2 < 8; ++h2) {
            v2 a = b1r[h2];
            #pragma unroll
            for (int p = 0; p < 8; ++p) {
                v2 xb = { x[p], x[p] };
                a = __builtin_elementwise_fma(xb, w1r[h2][p], a);
            }
            v2 t = tanh2(a);
            mu2 = __builtin_elementwise_fma(t, w2r[h2], mu2);
        }
        const float mu = mu2.x + mu2.y + b2s;

        out[b * NODES + n] = mu;                         // mus
        out[BATCH * NODES + b * NODES + n] = 0.f;        // logvars = 0

        g = gnext;
        b = bn;
    }
}

extern "C" void kernel_launch(void* const* d_in, const int* in_sizes, int n_in,
                              void* d_out, int out_size, void* d_ws, size_t ws_size,
                              hipStream_t stream)
{
    const float* gt  = (const float*)d_in[0];
    const float* W1  = (const float*)d_in[1];
    const float* b1  = (const float*)d_in[2];
    const float* W2  = (const float*)d_in[3];
    const float* b2  = (const float*)d_in[4];
    const int*   pix = (const int*)d_in[5];
    float* out = (float*)d_out;

    prior_kernel<<<NBLOCKS, TPB, 0, stream>>>(gt, W1, b1, W2, b2, pix, out);
}